// Round 1
// baseline (214.336 us; speedup 1.0000x reference)
//
#include <hip/hip_runtime.h>
#include <hip/hip_bf16.h>

// GRIN MoE feed-forward, routed top-2, bf16 MFMA grouped GEMM.
// T=4096 tokens, H=512, F=1024, E=8.

#define T_TOK 4096
#define HDIM  512
#define FDIM  1024
#define NEXP  8
#define MAXTILES 72   // sum_e ceil(cnt_e/128) <= 8192/128 + 8 = 72

typedef __attribute__((ext_vector_type(8))) __bf16 bf16x8;
typedef __attribute__((ext_vector_type(4))) float  f32x4;

__device__ __forceinline__ unsigned short f2bf(float f) {
  __hip_bfloat16 h = __float2bfloat16(f);
  return __builtin_bit_cast(unsigned short, h);
}

// ---------------- gating: scores -> sparsemixer top-2 -> per-expert lists ----
__global__ void gating_kernel(const float* __restrict__ x, const float* __restrict__ wg,
                              const float* __restrict__ bg, int* __restrict__ cnt,
                              int* __restrict__ idxl, float* __restrict__ wtl,
                              int* __restrict__ selpos) {
  int wv = threadIdx.x >> 6;
  int lane = threadIdx.x & 63;
  int t = blockIdx.x * 4 + wv;
  const float* xr = x + (size_t)t * HDIM + lane * 8;
  float4 xa = *reinterpret_cast<const float4*>(xr);
  float4 xb = *reinterpret_cast<const float4*>(xr + 4);
  float xv[8] = {xa.x, xa.y, xa.z, xa.w, xb.x, xb.y, xb.z, xb.w};
  float acc[8];
#pragma unroll
  for (int e = 0; e < 8; e++) acc[e] = 0.f;
  int h0 = lane * 8;
#pragma unroll
  for (int j = 0; j < 8; j++) {
    const float4* wr = reinterpret_cast<const float4*>(wg + (size_t)(h0 + j) * 8);
    float4 w0 = wr[0], w1 = wr[1];
    float xj = xv[j];
    acc[0] += xj * w0.x; acc[1] += xj * w0.y; acc[2] += xj * w0.z; acc[3] += xj * w0.w;
    acc[4] += xj * w1.x; acc[5] += xj * w1.y; acc[6] += xj * w1.z; acc[7] += xj * w1.w;
  }
#pragma unroll
  for (int s = 32; s >= 1; s >>= 1) {
#pragma unroll
    for (int e = 0; e < 8; e++) acc[e] += __shfl_xor(acc[e], s, 64);
  }
  if (lane == 0) {
    float sc[8];
    float mx = -1e30f;
    for (int e = 0; e < 8; e++) { sc[e] = acc[e] + bg[e]; mx = fmaxf(mx, sc[e]); }
    float sum = 0.f;
    for (int e = 0; e < 8; e++) { sc[e] = expf(sc[e] - mx); sum += sc[e]; }
    for (int e = 0; e < 8; e++) sc[e] /= sum;
    // ---- top-1 (first argmax, strict >) ----
    int s1 = 0; float mx1 = sc[0];
    for (int e = 1; e < 8; e++) if (sc[e] > mx1) { mx1 = sc[e]; s1 = e; }
    // masked softmax: kept iff !((mx1-sc)/mx1 > 0.02)  (scores>=0 so factor==mx1)
    float den1 = 0.f;
    for (int e = 0; e < 8; e++)
      if (!((mx1 - sc[e]) / mx1 > 0.02f)) den1 += expf(sc[e] - mx1);
    float mult1 = 1.0f / den1;   // exp(0)/den
    // ---- top-2 ----
    int s2 = 0; float mx2 = -1e30f;
    for (int e = 0; e < 8; e++) if (e != s1 && sc[e] > mx2) { mx2 = sc[e]; s2 = e; }
    float den2 = 0.f;
    for (int e = 0; e < 8; e++) {
      if (e == s1) continue;
      float fac = fmaxf(sc[e], mx2);
      if (!((mx2 - sc[e]) / fac > 0.02f)) den2 += expf(sc[e] - mx2);
    }
    float mult2 = 1.0f / den2;
    int p1 = atomicAdd(&cnt[s1], 1);
    idxl[s1 * T_TOK + p1] = t; wtl[s1 * T_TOK + p1] = mult1;
    selpos[2 * t] = (s1 << 16) | p1;
    int p2 = atomicAdd(&cnt[s2], 1);
    idxl[s2 * T_TOK + p2] = t; wtl[s2 * T_TOK + p2] = mult2;
    selpos[2 * t + 1] = (s2 << 16) | p2;
  }
}

// ---------------- prefix + tile schedule ----------------
__global__ void sched_kernel(const int* __restrict__ cnt, int* __restrict__ offs,
                             int2* __restrict__ sched) {
  if (threadIdx.x != 0 || blockIdx.x != 0) return;
  int c[8]; int a = 0;
  for (int e = 0; e < 8; e++) { c[e] = cnt[e]; offs[e] = a; a += c[e]; }
  int ti = 0;
  for (int e = 0; e < 8; e++)
    for (int b = 0; b < c[e]; b += 128) sched[ti++] = make_int2(e, b);
  for (; ti < MAXTILES; ti++) sched[ti] = make_int2(-1, 0);
}

// ---------------- x fp32 -> bf16 ----------------
__global__ void xconv_kernel(const float* __restrict__ x, unsigned short* __restrict__ xb) {
  int gid = blockIdx.x * blockDim.x + threadIdx.x;
  float4 v = reinterpret_cast<const float4*>(x)[gid];
  ushort4 o = {f2bf(v.x), f2bf(v.y), f2bf(v.z), f2bf(v.w)};
  reinterpret_cast<ushort4*>(xb)[gid] = o;
}

// ------- weight transpose+convert: src [E][R][C] f32 -> dst [E][C][R] bf16 ----
__global__ void transconv_kernel(const float* __restrict__ src, unsigned short* __restrict__ dst,
                                 int R, int C) {
  __shared__ float tile[32][33];
  int e = blockIdx.z;
  int rb = blockIdx.y * 32, cb = blockIdx.x * 32;
  int tr = threadIdx.x >> 3, tc = (threadIdx.x & 7) * 4;
  const float* s = src + ((size_t)e * R + rb + tr) * C + cb + tc;
  float4 v = *reinterpret_cast<const float4*>(s);
  tile[tc + 0][tr] = v.x; tile[tc + 1][tr] = v.y;
  tile[tc + 2][tr] = v.z; tile[tc + 3][tr] = v.w;
  __syncthreads();
  ushort4 o = {f2bf(tile[tr][tc]), f2bf(tile[tr][tc + 1]),
               f2bf(tile[tr][tc + 2]), f2bf(tile[tr][tc + 3])};
  *reinterpret_cast<ushort4*>(dst + ((size_t)e * C + cb + tr) * R + rb + tc) = o;
}

// ---------------- GEMM1: h = gelu(x@w1) * (x@w3) * wt  (gathered rows) -------
// A: gathered xb rows [128][K=512]; B: w1t/w3t [E][F][H] (N-major, K contig).
// LDS layout: 16B units, unit = row*8 + (u ^ (row&7))  (bank-conflict swizzle).
__global__ __launch_bounds__(256, 2) void gemm1_kernel(
    const unsigned short* __restrict__ xb, const unsigned short* __restrict__ w1t,
    const unsigned short* __restrict__ w3t, const int* __restrict__ idxl,
    const float* __restrict__ wtl, const int* __restrict__ cnt,
    const int* __restrict__ offs, const int2* __restrict__ sched,
    unsigned short* __restrict__ hbuf) {
  int2 sc = sched[blockIdx.y];
  if (sc.x < 0) return;
  int e = sc.x, base = sc.y;
  int cnte = cnt[e], off0 = offs[e];
  int rows = min(128, cnte - base);
  int n0 = blockIdx.x * 128;
  __shared__ uint4 Xs[1024], W1s[1024], W3s[1024];
  __shared__ int toks[128];
  __shared__ float wtls[128];
  int tid = threadIdx.x;
  if (tid < 128) {
    int r = min(tid, rows - 1);
    toks[tid] = idxl[e * T_TOK + base + r];
    wtls[tid] = (tid < rows) ? wtl[e * T_TOK + base + tid] : 0.f;
  }
  int lane = tid & 63, wv = tid >> 6;
  int wr = (wv >> 1) * 64, wc = (wv & 1) * 64;
  f32x4 accU[4][4], accV[4][4];
#pragma unroll
  for (int m = 0; m < 4; m++)
#pragma unroll
    for (int n = 0; n < 4; n++) {
      accU[m][n] = {0.f, 0.f, 0.f, 0.f};
      accV[m][n] = {0.f, 0.f, 0.f, 0.f};
    }
  int srow = tid >> 1, sh = tid & 1;
  size_t wb = ((size_t)e * FDIM + n0 + srow) * HDIM;
  __syncthreads();
  for (int k0 = 0; k0 < HDIM; k0 += 64) {
    const uint4* xg = reinterpret_cast<const uint4*>(xb + (size_t)toks[srow] * HDIM + k0);
    const uint4* g1 = reinterpret_cast<const uint4*>(w1t + wb + k0);
    const uint4* g3 = reinterpret_cast<const uint4*>(w3t + wb + k0);
#pragma unroll
    for (int j = 0; j < 4; j++) {
      int u = sh * 4 + j;
      int du = srow * 8 + (u ^ (srow & 7));
      Xs[du] = xg[u]; W1s[du] = g1[u]; W3s[du] = g3[u];
    }
    __syncthreads();
#pragma unroll
    for (int kk = 0; kk < 2; kk++) {
      int uc = kk * 4 + (lane >> 4);
      bf16x8 a[4], bu[4], bv[4];
#pragma unroll
      for (int m = 0; m < 4; m++) {
        int r = wr + m * 16 + (lane & 15);
        a[m] = __builtin_bit_cast(bf16x8, Xs[r * 8 + (uc ^ (r & 7))]);
      }
#pragma unroll
      for (int n = 0; n < 4; n++) {
        int r = wc + n * 16 + (lane & 15);
        bu[n] = __builtin_bit_cast(bf16x8, W1s[r * 8 + (uc ^ (r & 7))]);
        bv[n] = __builtin_bit_cast(bf16x8, W3s[r * 8 + (uc ^ (r & 7))]);
      }
#pragma unroll
      for (int m = 0; m < 4; m++)
#pragma unroll
        for (int n = 0; n < 4; n++) {
          accU[m][n] = __builtin_amdgcn_mfma_f32_16x16x32_bf16(a[m], bu[n], accU[m][n], 0, 0, 0);
          accV[m][n] = __builtin_amdgcn_mfma_f32_16x16x32_bf16(a[m], bv[n], accV[m][n], 0, 0, 0);
        }
    }
    __syncthreads();
  }
  // epilogue: h = gelu_exact(u) * v * token_weight -> bf16
#pragma unroll
  for (int m = 0; m < 4; m++) {
#pragma unroll
    for (int rr = 0; rr < 4; rr++) {
      int row = wr + m * 16 + ((lane >> 4) << 2) + rr;
      if (row < rows) {
        float wgt = wtls[row];
        size_t po = (size_t)(off0 + base + row) * FDIM + n0 + wc + (lane & 15);
#pragma unroll
        for (int n = 0; n < 4; n++) {
          float u = accU[m][n][rr], v = accV[m][n][rr];
          float h = 0.5f * u * (1.0f + erff(u * 0.707106781186547524f)) * v * wgt;
          hbuf[po + n * 16] = f2bf(h);
        }
      }
    }
  }
}

// ---------------- GEMM2: y = h @ w2  (contiguous slots) ----------------------
__global__ __launch_bounds__(256, 2) void gemm2_kernel(
    const unsigned short* __restrict__ hbuf, const unsigned short* __restrict__ w2t,
    const int* __restrict__ cnt, const int* __restrict__ offs,
    const int2* __restrict__ sched, float* __restrict__ y) {
  int2 sc = sched[blockIdx.y];
  if (sc.x < 0) return;
  int e = sc.x, base = sc.y;
  int cnte = cnt[e], off0 = offs[e];
  int rows = min(128, cnte - base);
  int n0 = blockIdx.x * 128;
  __shared__ uint4 As[1024], Bs[1024];
  int tid = threadIdx.x;
  int lane = tid & 63, wv = tid >> 6;
  int wr = (wv >> 1) * 64, wc = (wv & 1) * 64;
  f32x4 acc[4][4];
#pragma unroll
  for (int m = 0; m < 4; m++)
#pragma unroll
    for (int n = 0; n < 4; n++) acc[m][n] = {0.f, 0.f, 0.f, 0.f};
  int srow = tid >> 1, sh = tid & 1;
  size_t arow = (size_t)(off0 + base + min(srow, rows - 1)) * FDIM;
  size_t wb = ((size_t)e * HDIM + n0 + srow) * FDIM;
  for (int k0 = 0; k0 < FDIM; k0 += 64) {
    const uint4* ag = reinterpret_cast<const uint4*>(hbuf + arow + k0);
    const uint4* bgp = reinterpret_cast<const uint4*>(w2t + wb + k0);
#pragma unroll
    for (int j = 0; j < 4; j++) {
      int u = sh * 4 + j;
      int du = srow * 8 + (u ^ (srow & 7));
      As[du] = ag[u]; Bs[du] = bgp[u];
    }
    __syncthreads();
#pragma unroll
    for (int kk = 0; kk < 2; kk++) {
      int uc = kk * 4 + (lane >> 4);
      bf16x8 a[4], b[4];
#pragma unroll
      for (int m = 0; m < 4; m++) {
        int r = wr + m * 16 + (lane & 15);
        a[m] = __builtin_bit_cast(bf16x8, As[r * 8 + (uc ^ (r & 7))]);
      }
#pragma unroll
      for (int n = 0; n < 4; n++) {
        int r = wc + n * 16 + (lane & 15);
        b[n] = __builtin_bit_cast(bf16x8, Bs[r * 8 + (uc ^ (r & 7))]);
      }
#pragma unroll
      for (int m = 0; m < 4; m++)
#pragma unroll
        for (int n = 0; n < 4; n++)
          acc[m][n] = __builtin_amdgcn_mfma_f32_16x16x32_bf16(a[m], b[n], acc[m][n], 0, 0, 0);
    }
    __syncthreads();
  }
#pragma unroll
  for (int m = 0; m < 4; m++) {
#pragma unroll
    for (int rr = 0; rr < 4; rr++) {
      int row = wr + m * 16 + ((lane >> 4) << 2) + rr;
      if (row < rows) {
        size_t po = (size_t)(off0 + base + row) * HDIM + n0 + wc + (lane & 15);
#pragma unroll
        for (int n = 0; n < 4; n++) y[po + n * 16] = acc[m][n][rr];
      }
    }
  }
}

// ---------------- combine: out[t] = y[slot1] + y[slot2] ----------------------
__global__ void combine_kernel(const float* __restrict__ y, const int* __restrict__ selpos,
                               const int* __restrict__ offs, float* __restrict__ out) {
  int gid = blockIdx.x * blockDim.x + threadIdx.x;
  int ei = gid * 4;
  int t = ei >> 9;
  int c = ei & 511;
  int spA = selpos[2 * t], spB = selpos[2 * t + 1];
  int slotA = offs[spA >> 16] + (spA & 0xFFFF);
  int slotB = offs[spB >> 16] + (spB & 0xFFFF);
  float4 a = *reinterpret_cast<const float4*>(y + (size_t)slotA * HDIM + c);
  float4 b = *reinterpret_cast<const float4*>(y + (size_t)slotB * HDIM + c);
  float4 o = {a.x + b.x, a.y + b.y, a.z + b.z, a.w + b.w};
  *reinterpret_cast<float4*>(out + ei) = o;
}

// ---------------- launch ----------------------------------------------------
extern "C" void kernel_launch(void* const* d_in, const int* in_sizes, int n_in,
                              void* d_out, int out_size, void* d_ws, size_t ws_size,
                              hipStream_t stream) {
  const float* x  = (const float*)d_in[0];
  const float* wg = (const float*)d_in[1];
  const float* bg = (const float*)d_in[2];
  const float* w1 = (const float*)d_in[3];
  const float* w3 = (const float*)d_in[4];
  const float* w2 = (const float*)d_in[5];
  float* out = (float*)d_out;
  char* ws = (char*)d_ws;

  // workspace layout (needs ~61 MB)
  int*   cnt    = (int*)(ws + 0);            // 32 B
  int*   offs   = (int*)(ws + 64);           // 32 B
  int2*  sched  = (int2*)(ws + 128);         // 576 B
  int*   selpos = (int*)(ws + 1024);         // 32 KB
  int*   idxl   = (int*)(ws + 40960);        // 128 KB
  float* wtl    = (float*)(ws + 40960 + 131072);           // 128 KB
  unsigned short* xb   = (unsigned short*)(ws + (1ull << 20));   // 4 MB
  unsigned short* w1t  = (unsigned short*)(ws + (5ull << 20));   // 8 MB
  unsigned short* w3t  = (unsigned short*)(ws + (13ull << 20));  // 8 MB
  unsigned short* w2t  = (unsigned short*)(ws + (21ull << 20));  // 8 MB
  unsigned short* hbuf = (unsigned short*)(ws + (29ull << 20));  // 16 MB
  float* yb            = (float*)(ws + (45ull << 20));           // 16 MB

  hipMemsetAsync(cnt, 0, 32, stream);
  gating_kernel<<<T_TOK / 4, 256, 0, stream>>>(x, wg, bg, cnt, idxl, wtl, selpos);
  sched_kernel<<<1, 64, 0, stream>>>(cnt, offs, sched);
  xconv_kernel<<<(T_TOK * HDIM) / (256 * 4), 256, 0, stream>>>(x, xb);
  transconv_kernel<<<dim3(FDIM / 32, HDIM / 32, NEXP), 256, 0, stream>>>(w1, w1t, HDIM, FDIM);
  transconv_kernel<<<dim3(FDIM / 32, HDIM / 32, NEXP), 256, 0, stream>>>(w3, w3t, HDIM, FDIM);
  transconv_kernel<<<dim3(HDIM / 32, FDIM / 32, NEXP), 256, 0, stream>>>(w2, w2t, FDIM, HDIM);
  gemm1_kernel<<<dim3(FDIM / 128, MAXTILES), 256, 0, stream>>>(xb, w1t, w3t, idxl, wtl, cnt,
                                                               offs, sched, hbuf);
  gemm2_kernel<<<dim3(HDIM / 128, MAXTILES), 256, 0, stream>>>(hbuf, w2t, cnt, offs, sched, yb);
  combine_kernel<<<(T_TOK * HDIM) / (256 * 4), 256, 0, stream>>>(yb, selpos, offs, out);
}

// Round 2
// 130.750 us; speedup vs baseline: 1.6393x; 1.6393x over previous
//
#include <hip/hip_runtime.h>
#include <hip/hip_bf16.h>

// GRIN MoE feed-forward, routed top-2, bf16 MFMA grouped GEMM.
// T=4096 tokens, H=512, F=1024, E=8.
// R1: atomic-free routing (counting sort), fused x->bf16 into gating.

#define T_TOK 4096
#define HDIM  512
#define FDIM  1024
#define NEXP  8
#define MAXTILES 72

typedef __attribute__((ext_vector_type(8))) __bf16 bf16x8;
typedef __attribute__((ext_vector_type(4))) float  f32x4;

__device__ __forceinline__ unsigned int f2bf(float f) {
  __hip_bfloat16 h = __float2bfloat16(f);
  return (unsigned int)__builtin_bit_cast(unsigned short, h);
}

// ------- gating: scores -> sparsemixer top-2 -> selraw[t]; also x -> bf16 ----
__global__ void gating_score_kernel(const float* __restrict__ x, const float* __restrict__ wg,
                                    const float* __restrict__ bg, int4* __restrict__ selraw,
                                    unsigned short* __restrict__ xbuf) {
  int wv = threadIdx.x >> 6;
  int lane = threadIdx.x & 63;
  int t = blockIdx.x * 4 + wv;
  const float* xr = x + (size_t)t * HDIM + lane * 8;
  float4 xa = *reinterpret_cast<const float4*>(xr);
  float4 xb = *reinterpret_cast<const float4*>(xr + 4);
  // fused x -> bf16 (trunc-round via __float2bfloat16's RN is fine)
  uint4 o;
  o.x = f2bf(xa.x) | (f2bf(xa.y) << 16);
  o.y = f2bf(xa.z) | (f2bf(xa.w) << 16);
  o.z = f2bf(xb.x) | (f2bf(xb.y) << 16);
  o.w = f2bf(xb.z) | (f2bf(xb.w) << 16);
  *reinterpret_cast<uint4*>(xbuf + (size_t)t * HDIM + lane * 8) = o;

  float xv[8] = {xa.x, xa.y, xa.z, xa.w, xb.x, xb.y, xb.z, xb.w};
  float acc[8];
#pragma unroll
  for (int e = 0; e < 8; e++) acc[e] = 0.f;
  int h0 = lane * 8;
#pragma unroll
  for (int j = 0; j < 8; j++) {
    const float4* wr = reinterpret_cast<const float4*>(wg + (size_t)(h0 + j) * 8);
    float4 w0 = wr[0], w1 = wr[1];
    float xj = xv[j];
    acc[0] += xj * w0.x; acc[1] += xj * w0.y; acc[2] += xj * w0.z; acc[3] += xj * w0.w;
    acc[4] += xj * w1.x; acc[5] += xj * w1.y; acc[6] += xj * w1.z; acc[7] += xj * w1.w;
  }
#pragma unroll
  for (int s = 32; s >= 1; s >>= 1) {
#pragma unroll
    for (int e = 0; e < 8; e++) acc[e] += __shfl_xor(acc[e], s, 64);
  }
  if (lane == 0) {
    float sc[8];
    float mx = -1e30f;
    for (int e = 0; e < 8; e++) { sc[e] = acc[e] + bg[e]; mx = fmaxf(mx, sc[e]); }
    float sum = 0.f;
    for (int e = 0; e < 8; e++) { sc[e] = expf(sc[e] - mx); sum += sc[e]; }
    for (int e = 0; e < 8; e++) sc[e] /= sum;
    // ---- top-1 (first argmax, strict >) ----
    int s1 = 0; float mx1 = sc[0];
    for (int e = 1; e < 8; e++) if (sc[e] > mx1) { mx1 = sc[e]; s1 = e; }
    float den1 = 0.f;
    for (int e = 0; e < 8; e++)
      if (!((mx1 - sc[e]) / mx1 > 0.02f)) den1 += expf(sc[e] - mx1);
    float mult1 = 1.0f / den1;
    // ---- top-2 ----
    int s2 = 0; float mx2 = -1e30f;
    for (int e = 0; e < 8; e++) if (e != s1 && sc[e] > mx2) { mx2 = sc[e]; s2 = e; }
    float den2 = 0.f;
    for (int e = 0; e < 8; e++) {
      if (e == s1) continue;
      float fac = fmaxf(sc[e], mx2);
      if (!((mx2 - sc[e]) / fac > 0.02f)) den2 += expf(sc[e] - mx2);
    }
    float mult2 = 1.0f / den2;
    selraw[t] = make_int4(s1, s2, __float_as_int(mult1), __float_as_int(mult2));
  }
}

// ------- build: stable counting sort into per-expert lists + schedule --------
__global__ __launch_bounds__(256) void build_kernel(
    const int4* __restrict__ selraw, int* __restrict__ cnt, int* __restrict__ offs,
    int2* __restrict__ sched, int* __restrict__ idxl, float* __restrict__ wtl,
    int* __restrict__ selpos) {
  __shared__ int scan[256][8];   // running prefix (inclusive -> exclusive -> cursor)
  __shared__ int loc[256][8];    // per-thread local counts
  int tid = threadIdx.x;
#pragma unroll
  for (int e = 0; e < 8; e++) { scan[tid][e] = 0; loc[tid][e] = 0; }
  int t0 = tid * (T_TOK / 256);  // 16 tokens each
  int4 raw[T_TOK / 256];
#pragma unroll
  for (int i = 0; i < T_TOK / 256; i++) {
    raw[i] = selraw[t0 + i];
    loc[tid][raw[i].x]++;
    loc[tid][raw[i].y]++;
  }
#pragma unroll
  for (int e = 0; e < 8; e++) scan[tid][e] = loc[tid][e];
  __syncthreads();
  // Hillis-Steele inclusive scan over threads, all 8 experts at once
  for (int s = 1; s < 256; s <<= 1) {
    int v[8];
    if (tid >= s) {
#pragma unroll
      for (int e = 0; e < 8; e++) v[e] = scan[tid - s][e];
    }
    __syncthreads();
    if (tid >= s) {
#pragma unroll
      for (int e = 0; e < 8; e++) scan[tid][e] += v[e];
    }
    __syncthreads();
  }
  if (tid == 0) {
    int a = 0, ti = 0;
    for (int e = 0; e < 8; e++) {
      int ce = scan[255][e];
      cnt[e] = ce; offs[e] = a; a += ce;
    }
    for (int e = 0; e < 8; e++)
      for (int b = 0; b < scan[255][e]; b += 128) sched[ti++] = make_int2(e, b);
    for (; ti < MAXTILES; ti++) sched[ti] = make_int2(-1, 0);
  }
  // inclusive -> exclusive cursor (LDS, avoids runtime-indexed register array)
#pragma unroll
  for (int e = 0; e < 8; e++) scan[tid][e] -= loc[tid][e];
  __syncthreads();
#pragma unroll
  for (int i = 0; i < T_TOK / 256; i++) {
    int t = t0 + i;
    int s1 = raw[i].x, s2 = raw[i].y;
    int p1 = scan[tid][s1]++;
    idxl[s1 * T_TOK + p1] = t;
    wtl[s1 * T_TOK + p1] = __int_as_float(raw[i].z);
    selpos[2 * t] = (s1 << 16) | p1;
    int p2 = scan[tid][s2]++;
    idxl[s2 * T_TOK + p2] = t;
    wtl[s2 * T_TOK + p2] = __int_as_float(raw[i].w);
    selpos[2 * t + 1] = (s2 << 16) | p2;
  }
}

// ------- weight transpose+convert: [E][R][C] f32 -> [E][C][R] bf16 -----------
__global__ void transconv13_kernel(const float* __restrict__ s1p, const float* __restrict__ s3p,
                                   unsigned short* __restrict__ d1, unsigned short* __restrict__ d3) {
  __shared__ float tile[32][33];
  int z = blockIdx.z;
  const float* src = (z < NEXP) ? s1p : s3p;
  unsigned short* dst = (z < NEXP) ? d1 : d3;
  int e = z & 7;
  const int R = HDIM, C = FDIM;
  int rb = blockIdx.y * 32, cb = blockIdx.x * 32;
  int tr = threadIdx.x >> 3, tc = (threadIdx.x & 7) * 4;
  const float* s = src + ((size_t)e * R + rb + tr) * C + cb + tc;
  float4 v = *reinterpret_cast<const float4*>(s);
  tile[tc + 0][tr] = v.x; tile[tc + 1][tr] = v.y;
  tile[tc + 2][tr] = v.z; tile[tc + 3][tr] = v.w;
  __syncthreads();
  ushort4 o = {(unsigned short)f2bf(tile[tr][tc]), (unsigned short)f2bf(tile[tr][tc + 1]),
               (unsigned short)f2bf(tile[tr][tc + 2]), (unsigned short)f2bf(tile[tr][tc + 3])};
  *reinterpret_cast<ushort4*>(dst + ((size_t)e * C + cb + tr) * R + rb + tc) = o;
}

__global__ void transconv_kernel(const float* __restrict__ src, unsigned short* __restrict__ dst,
                                 int R, int C) {
  __shared__ float tile[32][33];
  int e = blockIdx.z;
  int rb = blockIdx.y * 32, cb = blockIdx.x * 32;
  int tr = threadIdx.x >> 3, tc = (threadIdx.x & 7) * 4;
  const float* s = src + ((size_t)e * R + rb + tr) * C + cb + tc;
  float4 v = *reinterpret_cast<const float4*>(s);
  tile[tc + 0][tr] = v.x; tile[tc + 1][tr] = v.y;
  tile[tc + 2][tr] = v.z; tile[tc + 3][tr] = v.w;
  __syncthreads();
  ushort4 o = {(unsigned short)f2bf(tile[tr][tc]), (unsigned short)f2bf(tile[tr][tc + 1]),
               (unsigned short)f2bf(tile[tr][tc + 2]), (unsigned short)f2bf(tile[tr][tc + 3])};
  *reinterpret_cast<ushort4*>(dst + ((size_t)e * C + cb + tr) * R + rb + tc) = o;
}

// ---------------- GEMM1: h = gelu(x@w1) * (x@w3) * wt  (gathered rows) -------
__global__ __launch_bounds__(256, 2) void gemm1_kernel(
    const unsigned short* __restrict__ xb, const unsigned short* __restrict__ w1t,
    const unsigned short* __restrict__ w3t, const int* __restrict__ idxl,
    const float* __restrict__ wtl, const int* __restrict__ cnt,
    const int* __restrict__ offs, const int2* __restrict__ sched,
    unsigned short* __restrict__ hbuf) {
  int2 sc = sched[blockIdx.y];
  if (sc.x < 0) return;
  int e = sc.x, base = sc.y;
  int cnte = cnt[e], off0 = offs[e];
  int rows = min(128, cnte - base);
  int n0 = blockIdx.x * 128;
  __shared__ uint4 Xs[1024], W1s[1024], W3s[1024];
  __shared__ int toks[128];
  __shared__ float wtls[128];
  int tid = threadIdx.x;
  if (tid < 128) {
    int r = min(tid, rows - 1);
    toks[tid] = idxl[e * T_TOK + base + r];
    wtls[tid] = (tid < rows) ? wtl[e * T_TOK + base + tid] : 0.f;
  }
  int lane = tid & 63, wv = tid >> 6;
  int wr = (wv >> 1) * 64, wc = (wv & 1) * 64;
  f32x4 accU[4][4], accV[4][4];
#pragma unroll
  for (int m = 0; m < 4; m++)
#pragma unroll
    for (int n = 0; n < 4; n++) {
      accU[m][n] = {0.f, 0.f, 0.f, 0.f};
      accV[m][n] = {0.f, 0.f, 0.f, 0.f};
    }
  int srow = tid >> 1, sh = tid & 1;
  size_t wb = ((size_t)e * FDIM + n0 + srow) * HDIM;
  __syncthreads();
  for (int k0 = 0; k0 < HDIM; k0 += 64) {
    const uint4* xg = reinterpret_cast<const uint4*>(xb + (size_t)toks[srow] * HDIM + k0);
    const uint4* g1 = reinterpret_cast<const uint4*>(w1t + wb + k0);
    const uint4* g3 = reinterpret_cast<const uint4*>(w3t + wb + k0);
#pragma unroll
    for (int j = 0; j < 4; j++) {
      int u = sh * 4 + j;
      int du = srow * 8 + (u ^ (srow & 7));
      Xs[du] = xg[u]; W1s[du] = g1[u]; W3s[du] = g3[u];
    }
    __syncthreads();
#pragma unroll
    for (int kk = 0; kk < 2; kk++) {
      int uc = kk * 4 + (lane >> 4);
      bf16x8 a[4], bu[4], bv[4];
#pragma unroll
      for (int m = 0; m < 4; m++) {
        int r = wr + m * 16 + (lane & 15);
        a[m] = __builtin_bit_cast(bf16x8, Xs[r * 8 + (uc ^ (r & 7))]);
      }
#pragma unroll
      for (int n = 0; n < 4; n++) {
        int r = wc + n * 16 + (lane & 15);
        bu[n] = __builtin_bit_cast(bf16x8, W1s[r * 8 + (uc ^ (r & 7))]);
        bv[n] = __builtin_bit_cast(bf16x8, W3s[r * 8 + (uc ^ (r & 7))]);
      }
#pragma unroll
      for (int m = 0; m < 4; m++)
#pragma unroll
        for (int n = 0; n < 4; n++) {
          accU[m][n] = __builtin_amdgcn_mfma_f32_16x16x32_bf16(a[m], bu[n], accU[m][n], 0, 0, 0);
          accV[m][n] = __builtin_amdgcn_mfma_f32_16x16x32_bf16(a[m], bv[n], accV[m][n], 0, 0, 0);
        }
    }
    __syncthreads();
  }
#pragma unroll
  for (int m = 0; m < 4; m++) {
#pragma unroll
    for (int rr = 0; rr < 4; rr++) {
      int row = wr + m * 16 + ((lane >> 4) << 2) + rr;
      if (row < rows) {
        float wgt = wtls[row];
        size_t po = (size_t)(off0 + base + row) * FDIM + n0 + wc + (lane & 15);
#pragma unroll
        for (int n = 0; n < 4; n++) {
          float u = accU[m][n][rr], v = accV[m][n][rr];
          float h = 0.5f * u * (1.0f + erff(u * 0.707106781186547524f)) * v * wgt;
          hbuf[po + n * 16] = (unsigned short)f2bf(h);
        }
      }
    }
  }
}

// ---------------- GEMM2: y = h @ w2  (contiguous slots) ----------------------
__global__ __launch_bounds__(256, 2) void gemm2_kernel(
    const unsigned short* __restrict__ hbuf, const unsigned short* __restrict__ w2t,
    const int* __restrict__ cnt, const int* __restrict__ offs,
    const int2* __restrict__ sched, float* __restrict__ y) {
  int2 sc = sched[blockIdx.y];
  if (sc.x < 0) return;
  int e = sc.x, base = sc.y;
  int cnte = cnt[e], off0 = offs[e];
  int rows = min(128, cnte - base);
  int n0 = blockIdx.x * 128;
  __shared__ uint4 As[1024], Bs[1024];
  int tid = threadIdx.x;
  int lane = tid & 63, wv = tid >> 6;
  int wr = (wv >> 1) * 64, wc = (wv & 1) * 64;
  f32x4 acc[4][4];
#pragma unroll
  for (int m = 0; m < 4; m++)
#pragma unroll
    for (int n = 0; n < 4; n++) acc[m][n] = {0.f, 0.f, 0.f, 0.f};
  int srow = tid >> 1, sh = tid & 1;
  size_t arow = (size_t)(off0 + base + min(srow, rows - 1)) * FDIM;
  size_t wb = ((size_t)e * HDIM + n0 + srow) * FDIM;
  for (int k0 = 0; k0 < FDIM; k0 += 64) {
    const uint4* ag = reinterpret_cast<const uint4*>(hbuf + arow + k0);
    const uint4* bgp = reinterpret_cast<const uint4*>(w2t + wb + k0);
#pragma unroll
    for (int j = 0; j < 4; j++) {
      int u = sh * 4 + j;
      int du = srow * 8 + (u ^ (srow & 7));
      As[du] = ag[u]; Bs[du] = bgp[u];
    }
    __syncthreads();
#pragma unroll
    for (int kk = 0; kk < 2; kk++) {
      int uc = kk * 4 + (lane >> 4);
      bf16x8 a[4], b[4];
#pragma unroll
      for (int m = 0; m < 4; m++) {
        int r = wr + m * 16 + (lane & 15);
        a[m] = __builtin_bit_cast(bf16x8, As[r * 8 + (uc ^ (r & 7))]);
      }
#pragma unroll
      for (int n = 0; n < 4; n++) {
        int r = wc + n * 16 + (lane & 15);
        b[n] = __builtin_bit_cast(bf16x8, Bs[r * 8 + (uc ^ (r & 7))]);
      }
#pragma unroll
      for (int m = 0; m < 4; m++)
#pragma unroll
        for (int n = 0; n < 4; n++)
          acc[m][n] = __builtin_amdgcn_mfma_f32_16x16x32_bf16(a[m], b[n], acc[m][n], 0, 0, 0);
    }
    __syncthreads();
  }
#pragma unroll
  for (int m = 0; m < 4; m++) {
#pragma unroll
    for (int rr = 0; rr < 4; rr++) {
      int row = wr + m * 16 + ((lane >> 4) << 2) + rr;
      if (row < rows) {
        size_t po = (size_t)(off0 + base + row) * HDIM + n0 + wc + (lane & 15);
#pragma unroll
        for (int n = 0; n < 4; n++) y[po + n * 16] = acc[m][n][rr];
      }
    }
  }
}

// ---------------- combine: out[t] = y[slot1] + y[slot2] ----------------------
__global__ void combine_kernel(const float* __restrict__ y, const int* __restrict__ selpos,
                               const int* __restrict__ offs, float* __restrict__ out) {
  int gid = blockIdx.x * blockDim.x + threadIdx.x;
  int ei = gid * 4;
  int t = ei >> 9;
  int c = ei & 511;
  int spA = selpos[2 * t], spB = selpos[2 * t + 1];
  int slotA = offs[spA >> 16] + (spA & 0xFFFF);
  int slotB = offs[spB >> 16] + (spB & 0xFFFF);
  float4 a = *reinterpret_cast<const float4*>(y + (size_t)slotA * HDIM + c);
  float4 b = *reinterpret_cast<const float4*>(y + (size_t)slotB * HDIM + c);
  float4 o = {a.x + b.x, a.y + b.y, a.z + b.z, a.w + b.w};
  *reinterpret_cast<float4*>(out + ei) = o;
}

// ---------------- launch ----------------------------------------------------
extern "C" void kernel_launch(void* const* d_in, const int* in_sizes, int n_in,
                              void* d_out, int out_size, void* d_ws, size_t ws_size,
                              hipStream_t stream) {
  const float* x  = (const float*)d_in[0];
  const float* wg = (const float*)d_in[1];
  const float* bg = (const float*)d_in[2];
  const float* w1 = (const float*)d_in[3];
  const float* w3 = (const float*)d_in[4];
  const float* w2 = (const float*)d_in[5];
  float* out = (float*)d_out;
  char* ws = (char*)d_ws;

  int*   cnt    = (int*)(ws + 0);
  int*   offs   = (int*)(ws + 64);
  int2*  sched  = (int2*)(ws + 128);
  int*   selpos = (int*)(ws + 1024);                       // 32 KB
  int4*  selraw = (int4*)(ws + 65536);                     // 64 KB
  int*   idxl   = (int*)(ws + 131072);                     // 128 KB
  float* wtl    = (float*)(ws + 262144);                   // 128 KB
  unsigned short* xb   = (unsigned short*)(ws + (1ull << 20));   // 4 MB
  unsigned short* w1t  = (unsigned short*)(ws + (5ull << 20));   // 8 MB
  unsigned short* w3t  = (unsigned short*)(ws + (13ull << 20));  // 8 MB
  unsigned short* w2t  = (unsigned short*)(ws + (21ull << 20));  // 8 MB
  unsigned short* hbuf = (unsigned short*)(ws + (29ull << 20));  // 16 MB
  float* yb            = (float*)(ws + (45ull << 20));           // 16 MB

  gating_score_kernel<<<T_TOK / 4, 256, 0, stream>>>(x, wg, bg, selraw, xb);
  build_kernel<<<1, 256, 0, stream>>>(selraw, cnt, offs, sched, idxl, wtl, selpos);
  transconv13_kernel<<<dim3(FDIM / 32, HDIM / 32, 2 * NEXP), 256, 0, stream>>>(w1, w3, w1t, w3t);
  transconv_kernel<<<dim3(HDIM / 32, FDIM / 32, NEXP), 256, 0, stream>>>(w2, w2t, FDIM, HDIM);
  gemm1_kernel<<<dim3(FDIM / 128, MAXTILES), 256, 0, stream>>>(xb, w1t, w3t, idxl, wtl, cnt,
                                                               offs, sched, hbuf);
  gemm2_kernel<<<dim3(HDIM / 128, MAXTILES), 256, 0, stream>>>(hbuf, w2t, cnt, offs, sched, yb);
  combine_kernel<<<(T_TOK * HDIM) / (256 * 4), 256, 0, stream>>>(yb, selpos, offs, out);
}